// Round 7
// baseline (1986.526 us; speedup 1.0000x reference)
//
#include <hip/hip_runtime.h>
#include <hip/hip_bf16.h>

typedef unsigned short u16;
typedef unsigned int u32;
typedef __attribute__((ext_vector_type(8))) short bf16x8;   // 8 bf16 = 4 VGPRs
typedef __attribute__((ext_vector_type(4))) float f32x4;

#define MFMA16(A, B, C) __builtin_amdgcn_mfma_f32_16x16x32_bf16((A), (B), (C), 0, 0, 0)

// tanh(x) = 1 - 2/(e^{2x}+1); exp2-based, saturates correctly at +/-inf
static __device__ __forceinline__ float fast_tanh(float x) {
  float e = __builtin_amdgcn_exp2f(x * 2.8853900817779268f);  // e^(2x)
  return 1.0f - 2.0f * __builtin_amdgcn_rcpf(e + 1.0f);
}
static __device__ __forceinline__ u16 f2bf(float f) {  // RNE fp32->bf16 (scalar)
  unsigned u = __builtin_bit_cast(unsigned, f);
  u += 0x7fffu + ((u >> 16) & 1u);
  return (u16)(u >> 16);
}
static __device__ __forceinline__ float bf2f(u16 h) {
  unsigned u = ((unsigned)h) << 16;
  return __builtin_bit_cast(float, u);
}
static __device__ __forceinline__ float bf2f_lo(u32 w) {  // low bf16 of pair
  return __builtin_bit_cast(float, w << 16);
}
static __device__ __forceinline__ float bf2f_hi(u32 w) {  // high bf16 of pair
  return __builtin_bit_cast(float, w & 0xffff0000u);
}
// pack 2 fp32 -> packed bf16x2; .x = low u16
static __device__ __forceinline__ u32 pk2(float a, float b) {
  __hip_bfloat162 h = __float22bfloat162_rn(make_float2(a, b));
  union { __hip_bfloat162 h; u32 u; } cv;
  cv.h = h;
  return cv.u;
}

// Gather one MFMA weight fragment: lane (q,c) element j holds W[r0+j][col].
// Used as the A operand (A[m=col][k=r0+j] of W^T).
static __device__ __forceinline__ bf16x8 load_wfrag(const void* W, bool isbf,
                                                    int N, int r0, int col) {
  union { bf16x8 v; u16 s[8]; } u;
  if (isbf) {
    const u16* p = (const u16*)W;
#pragma unroll
    for (int j = 0; j < 8; ++j) u.s[j] = p[(r0 + j) * N + col];
  } else {
    const float* p = (const float*)W;
#pragma unroll
    for (int j = 0; j < 8; ++j) u.s[j] = f2bf(p[(r0 + j) * N + col]);
  }
  return u.v;
}
static __device__ __forceinline__ float ldb(const void* p, bool isbf, int i) {
  return isbf ? bf2f(((const u16*)p)[i]) : ((const float*)p)[i];
}

// ---------------------------------------------------------------------------
// Fused NeuralODE, transposed world: z^T = W^T @ h^T per GEMM.
// 256 threads = 4 waves, 4-way feature split; weights register/AGPR-resident.
// R6 lesson: at 1 wave/SIMD there is no TLP to hide ds_read latency -> 60%
// stall. Fix here: TWO independent batch tiles (T0,T1) per block, phases
// interleaved (GEMM1(T0);GEMM1(T1);barrier;...) -> ILP within the wave hides
// latency, and barriers per f-eval drop 3 -> 1.5. Per-element fp32 op
// sequence is bitwise-identical to R4/R6 (PASS numerics frozen).
// ---------------------------------------------------------------------------
__global__ __launch_bounds__(256, 1) void node_main(
    const void* __restrict__ xv, void* __restrict__ outv,
    const void* __restrict__ Wenc, const void* __restrict__ benc,
    const void* __restrict__ W1, const void* __restrict__ b1,
    const void* __restrict__ W2, const void* __restrict__ b2,
    const void* __restrict__ W3, const void* __restrict__ b3,
    const void* __restrict__ Wdec, const void* __restrict__ bdec) {
  constexpr int STR = 264;  // 256 + 8 pad (keeps 16B alignment of fragments)
  // 4 buffers: tile0 ping/pong, tile1 ping/pong  (4 x 16.9 KB = 67.6 KB)
  __shared__ __align__(16) u16 zbA0[32 * STR], zbB0[32 * STR];
  __shared__ __align__(16) u16 zbA1[32 * STR], zbB1[32 * STR];

  const int tid = threadIdx.x;
  const int w = tid >> 6, L = tid & 63;   // w in 0..3
  const int q = L >> 4, c = L & 15;
  const float dt = 0.05f;

  // ---- runtime dtype detection (uniform) ----
  int cnt = 0;
  {
    const unsigned* wu = (const unsigned*)Wenc;
#pragma unroll 1
    for (int i = 0; i < 64; ++i) {
      unsigned e = (wu[i] >> 7) & 0xFFu;
      cnt += (e >= 110u && e <= 124u) ? 1 : 0;
    }
  }
  const bool isbf = (cnt >= 32);

  // ---- register/AGPR-resident weight A-frags (per-wave feature slice) ----
  bf16x8 wef[2][2], w1f[4][4], w2f[8][4], w3f[8][2], wdf[4];
#pragma unroll
  for (int kt = 0; kt < 2; ++kt)
#pragma unroll
    for (int mt = 0; mt < 2; ++mt)
      wef[kt][mt] = load_wfrag(Wenc, isbf, 128, kt * 32 + q * 8, 32 * w + mt * 16 + c);
#pragma unroll
  for (int kt = 0; kt < 4; ++kt)
#pragma unroll
    for (int mt = 0; mt < 4; ++mt)
      w1f[kt][mt] = load_wfrag(W1, isbf, 256, kt * 32 + q * 8, 64 * w + mt * 16 + c);
#pragma unroll
  for (int kt = 0; kt < 8; ++kt)
#pragma unroll
    for (int mt = 0; mt < 4; ++mt)
      w2f[kt][mt] = load_wfrag(W2, isbf, 256, kt * 32 + q * 8, 64 * w + mt * 16 + c);
#pragma unroll
  for (int kt = 0; kt < 8; ++kt)
#pragma unroll
    for (int mt = 0; mt < 2; ++mt)
      w3f[kt][mt] = load_wfrag(W3, isbf, 128, kt * 32 + q * 8, 32 * w + mt * 16 + c);
#pragma unroll
  for (int kt = 0; kt < 4; ++kt)
    wdf[kt] = load_wfrag(Wdec, isbf, 64, kt * 32 + q * 8, 16 * w + c);

  // ---- biases, all stored packed bf16 pairs (register diet). Unpacking
  // reproduces the exact fp32 values (sources are bf16). ----
  u32 b1p[4][2], b2p[4][2];   // [mt]: feats 64w+16mt+4q+{0,1}/{2,3}
#pragma unroll
  for (int mt = 0; mt < 4; ++mt) {
    int base = 64 * w + 16 * mt + 4 * q;
    b1p[mt][0] = pk2(ldb(b1, isbf, base + 0), ldb(b1, isbf, base + 1));
    b1p[mt][1] = pk2(ldb(b1, isbf, base + 2), ldb(b1, isbf, base + 3));
    b2p[mt][0] = pk2(ldb(b2, isbf, base + 0), ldb(b2, isbf, base + 1));
    b2p[mt][1] = pk2(ldb(b2, isbf, base + 2), ldb(b2, isbf, base + 3));
  }
  u32 bep[2][2], b3p[2][2], bdp[2];
#pragma unroll
  for (int mt = 0; mt < 2; ++mt) {
    int base = 32 * w + 16 * mt + 4 * q;
    bep[mt][0] = pk2(ldb(benc, isbf, base + 0), ldb(benc, isbf, base + 1));
    bep[mt][1] = pk2(ldb(benc, isbf, base + 2), ldb(benc, isbf, base + 3));
    b3p[mt][0] = pk2(ldb(b3, isbf, base + 0), ldb(b3, isbf, base + 1));
    b3p[mt][1] = pk2(ldb(b3, isbf, base + 2), ldb(b3, isbf, base + 3));
  }
  bdp[0] = pk2(ldb(bdec, isbf, 16 * w + 4 * q + 0), ldb(bdec, isbf, 16 * w + 4 * q + 1));
  bdp[1] = pk2(ldb(bdec, isbf, 16 * w + 4 * q + 2), ldb(bdec, isbf, 16 * w + 4 * q + 3));

  // ODE state for both tiles: [tile][mt][nt][i], feats 32w+16mt+4q+i
  float h[2][2][2][4], r[2][2][2][4];

  // Paired f-eval. For tile t: htmp in P[t] -> z1 in Q[t] -> z2 in P[t] ->
  // k (regs) -> htmp' in Q[t]. Call sites swap P/Q each step.
  auto feval2 = [&](int j, u16* __restrict__ P0, u16* __restrict__ Q0,
                    u16* __restrict__ P1, u16* __restrict__ Q1)
      __attribute__((always_inline)) {
    u16* const P[2] = {P0, P1};
    u16* const Q[2] = {Q0, Q1};
    f32x4 acc[4][2];

    // ---- phase 1: GEMM1 both tiles: z1 = tanh(W1^T @ htmp + b1), K=128 ----
#pragma unroll
    for (int t = 0; t < 2; ++t) {
#pragma unroll
      for (int mt = 0; mt < 4; ++mt) {
        f32x4 bi = (f32x4){bf2f_lo(b1p[mt][0]), bf2f_hi(b1p[mt][0]),
                           bf2f_lo(b1p[mt][1]), bf2f_hi(b1p[mt][1])};
        acc[mt][0] = bi;
        acc[mt][1] = bi;
      }
#pragma unroll
      for (int kt = 0; kt < 4; ++kt) {
        bf16x8 bb0 = *(const bf16x8*)(P[t] + c * STR + kt * 32 + 8 * q);
        bf16x8 bb1 = *(const bf16x8*)(P[t] + (16 + c) * STR + kt * 32 + 8 * q);
#pragma unroll
        for (int mt = 0; mt < 4; ++mt) {
          acc[mt][0] = MFMA16(w1f[kt][mt], bb0, acc[mt][0]);
          acc[mt][1] = MFMA16(w1f[kt][mt], bb1, acc[mt][1]);
        }
      }
#pragma unroll
      for (int mt = 0; mt < 4; ++mt)
#pragma unroll
        for (int nt = 0; nt < 2; ++nt) {
          float t0 = fast_tanh(acc[mt][nt][0]), t1 = fast_tanh(acc[mt][nt][1]);
          float t2 = fast_tanh(acc[mt][nt][2]), t3 = fast_tanh(acc[mt][nt][3]);
          uint2 v; v.x = pk2(t0, t1); v.y = pk2(t2, t3);
          *(uint2*)(Q[t] + (nt * 16 + c) * STR + 64 * w + 16 * mt + 4 * q) = v;
        }
    }
    __syncthreads();

    // ---- phase 2: GEMM2 both tiles: z2 = tanh(W2^T @ z1 + b2), K=256 ----
#pragma unroll
    for (int t = 0; t < 2; ++t) {
#pragma unroll
      for (int mt = 0; mt < 4; ++mt) {
        f32x4 bi = (f32x4){bf2f_lo(b2p[mt][0]), bf2f_hi(b2p[mt][0]),
                           bf2f_lo(b2p[mt][1]), bf2f_hi(b2p[mt][1])};
        acc[mt][0] = bi;
        acc[mt][1] = bi;
      }
#pragma unroll
      for (int kt = 0; kt < 8; ++kt) {
        bf16x8 bb0 = *(const bf16x8*)(Q[t] + c * STR + kt * 32 + 8 * q);
        bf16x8 bb1 = *(const bf16x8*)(Q[t] + (16 + c) * STR + kt * 32 + 8 * q);
#pragma unroll
        for (int mt = 0; mt < 4; ++mt) {
          acc[mt][0] = MFMA16(w2f[kt][mt], bb0, acc[mt][0]);
          acc[mt][1] = MFMA16(w2f[kt][mt], bb1, acc[mt][1]);
        }
      }
      // After phase-1 barrier nobody reads P[t] until the next barrier, so
      // overwriting P[t] here is race-free.
#pragma unroll
      for (int mt = 0; mt < 4; ++mt)
#pragma unroll
        for (int nt = 0; nt < 2; ++nt) {
          float t0 = fast_tanh(acc[mt][nt][0]), t1 = fast_tanh(acc[mt][nt][1]);
          float t2 = fast_tanh(acc[mt][nt][2]), t3 = fast_tanh(acc[mt][nt][3]);
          uint2 v; v.x = pk2(t0, t1); v.y = pk2(t2, t3);
          *(uint2*)(P[t] + (nt * 16 + c) * STR + 64 * w + 16 * mt + 4 * q) = v;
        }
    }
    __syncthreads();

    // ---- phase 3: GEMM3 + RK4 both tiles: k = W3^T @ z2 + b3, K=256 ----
    const float wc = (j == 1 || j == 2) ? 2.f : 1.f;
    const float cc = (j == 2) ? dt : 0.5f * dt;
#pragma unroll
    for (int t = 0; t < 2; ++t) {
      f32x4 ak[2][2];
#pragma unroll
      for (int mt = 0; mt < 2; ++mt) {
        f32x4 bi = (f32x4){bf2f_lo(b3p[mt][0]), bf2f_hi(b3p[mt][0]),
                           bf2f_lo(b3p[mt][1]), bf2f_hi(b3p[mt][1])};
        ak[mt][0] = bi;
        ak[mt][1] = bi;
      }
#pragma unroll
      for (int kt = 0; kt < 8; ++kt) {
        bf16x8 bb0 = *(const bf16x8*)(P[t] + c * STR + kt * 32 + 8 * q);
        bf16x8 bb1 = *(const bf16x8*)(P[t] + (16 + c) * STR + kt * 32 + 8 * q);
#pragma unroll
        for (int mt = 0; mt < 2; ++mt) {
          ak[mt][0] = MFMA16(w3f[kt][mt], bb0, ak[mt][0]);
          ak[mt][1] = MFMA16(w3f[kt][mt], bb1, ak[mt][1]);
        }
      }
#pragma unroll
      for (int mt = 0; mt < 2; ++mt)
#pragma unroll
        for (int nt = 0; nt < 2; ++nt) {
          float ht[4];
#pragma unroll
          for (int i = 0; i < 4; ++i) {
            float kv = ak[mt][nt][i];
            float rv = (j == 0) ? kv : r[t][mt][nt][i] + wc * kv;
            r[t][mt][nt][i] = rv;
            if (j == 3) {
              h[t][mt][nt][i] += (dt / 6.f) * rv;
              ht[i] = h[t][mt][nt][i];
            } else {
              ht[i] = h[t][mt][nt][i] + cc * kv;
            }
          }
          uint2 v; v.x = pk2(ht[0], ht[1]); v.y = pk2(ht[2], ht[3]);
          *(uint2*)(Q[t] + (nt * 16 + c) * STR + 32 * w + 16 * mt + 4 * q) = v;
        }
    }
    __syncthreads();
  };

#pragma unroll 1
  for (int t0 = blockIdx.x; t0 < 1024; t0 += 256) {
    const int tiles[2] = {t0, t0 + 1024};
    u16* const enc_dst[2] = {zbA0, zbA1};

    // ---- encoders (both tiles): h0 = tanh(Wenc^T @ x^T + benc) ----
#pragma unroll
    for (int t = 0; t < 2; ++t) {
      const int row0 = tiles[t] * 32;
      f32x4 he[2][2];
#pragma unroll
      for (int mt = 0; mt < 2; ++mt) {
        f32x4 bi = (f32x4){bf2f_lo(bep[mt][0]), bf2f_hi(bep[mt][0]),
                           bf2f_lo(bep[mt][1]), bf2f_hi(bep[mt][1])};
        he[mt][0] = bi;
        he[mt][1] = bi;
      }
#pragma unroll
      for (int kt = 0; kt < 2; ++kt)
#pragma unroll
        for (int nt = 0; nt < 2; ++nt) {
          bf16x8 a;
          const int off = (row0 + nt * 16 + c) * 64 + kt * 32 + q * 8;
          if (isbf) {
            a = *(const bf16x8*)((const u16*)xv + off);
          } else {
            union { bf16x8 v; u16 s[8]; } u;
            const float* p = (const float*)xv + off;
#pragma unroll
            for (int j = 0; j < 8; ++j) u.s[j] = f2bf(p[j]);
            a = u.v;
          }
#pragma unroll
          for (int mt = 0; mt < 2; ++mt)
            he[mt][nt] = MFMA16(wef[kt][mt], a, he[mt][nt]);
        }
#pragma unroll
      for (int mt = 0; mt < 2; ++mt)
#pragma unroll
        for (int nt = 0; nt < 2; ++nt) {
#pragma unroll
          for (int i = 0; i < 4; ++i) h[t][mt][nt][i] = fast_tanh(he[mt][nt][i]);
          uint2 v;
          v.x = pk2(h[t][mt][nt][0], h[t][mt][nt][1]);
          v.y = pk2(h[t][mt][nt][2], h[t][mt][nt][3]);
          *(uint2*)(enc_dst[t] + (nt * 16 + c) * STR + 32 * w + 16 * mt + 4 * q) = v;
        }
    }
    __syncthreads();

#pragma unroll 1
    for (int s = 0; s < 20; ++s) {
      feval2(0, zbA0, zbB0, zbA1, zbB1);
      feval2(1, zbB0, zbA0, zbB1, zbA1);
      feval2(2, zbA0, zbB0, zbA1, zbB1);
      feval2(3, zbB0, zbA0, zbB1, zbA1);
    }

    // ---- decoders (both tiles): out = Wdec^T @ hT + bdec, K=128 ----
#pragma unroll
    for (int t = 0; t < 2; ++t) {
      const int row0 = tiles[t] * 32;
      const u16* src = enc_dst[t];  // after 80 (even) swaps hT is back in A
      f32x4 ad[2];
      f32x4 bi = (f32x4){bf2f_lo(bdp[0]), bf2f_hi(bdp[0]),
                         bf2f_lo(bdp[1]), bf2f_hi(bdp[1])};
      ad[0] = bi; ad[1] = bi;
#pragma unroll
      for (int kt = 0; kt < 4; ++kt) {
        bf16x8 bb0 = *(const bf16x8*)(src + c * STR + kt * 32 + 8 * q);
        bf16x8 bb1 = *(const bf16x8*)(src + (16 + c) * STR + kt * 32 + 8 * q);
        ad[0] = MFMA16(wdf[kt], bb0, ad[0]);
        ad[1] = MFMA16(wdf[kt], bb1, ad[1]);
      }
#pragma unroll
      for (int nt = 0; nt < 2; ++nt) {
        const int ob = row0 + nt * 16 + c;        // batch row
        const int of = 16 * w + 4 * q;            // feature col (4 contiguous)
        if (isbf) {
          uint2 v; v.x = pk2(ad[nt][0], ad[nt][1]); v.y = pk2(ad[nt][2], ad[nt][3]);
          *(uint2*)((u16*)outv + ob * 64 + of) = v;
        } else {
#pragma unroll
          for (int i = 0; i < 4; ++i) ((float*)outv)[ob * 64 + of + i] = ad[nt][i];
        }
      }
    }
    __syncthreads();  // protect buffers before next pair's encoders
  }
}

extern "C" void kernel_launch(void* const* d_in, const int* in_sizes, int n_in,
                              void* d_out, int out_size, void* d_ws, size_t ws_size,
                              hipStream_t stream) {
  (void)in_sizes; (void)n_in; (void)out_size; (void)d_ws; (void)ws_size;
  node_main<<<256, 256, 0, stream>>>(
      d_in[0], d_out,
      d_in[1], d_in[2],   // W_enc, b_enc
      d_in[3], d_in[4],   // W1, b1
      d_in[5], d_in[6],   // W2, b2
      d_in[7], d_in[8],   // W3, b3
      d_in[9], d_in[10]); // W_dec, b_dec
}

// Round 8
// 1602.239 us; speedup vs baseline: 1.2398x; 1.2398x over previous
//
#include <hip/hip_runtime.h>
#include <hip/hip_bf16.h>

typedef unsigned short u16;
typedef unsigned int u32;
typedef __attribute__((ext_vector_type(8))) short bf16x8;   // 8 bf16 = 4 VGPRs
typedef __attribute__((ext_vector_type(4))) float f32x4;

#define MFMA16(A, B, C) __builtin_amdgcn_mfma_f32_16x16x32_bf16((A), (B), (C), 0, 0, 0)

// tanh(x) = 1 - 2/(e^{2x}+1); exp2-based, saturates correctly at +/-inf
static __device__ __forceinline__ float fast_tanh(float x) {
  float e = __builtin_amdgcn_exp2f(x * 2.8853900817779268f);  // e^(2x)
  return 1.0f - 2.0f * __builtin_amdgcn_rcpf(e + 1.0f);
}
static __device__ __forceinline__ u16 f2bf(float f) {  // RNE fp32->bf16 (scalar)
  unsigned u = __builtin_bit_cast(unsigned, f);
  u += 0x7fffu + ((u >> 16) & 1u);
  return (u16)(u >> 16);
}
static __device__ __forceinline__ float bf2f(u16 h) {
  unsigned u = ((unsigned)h) << 16;
  return __builtin_bit_cast(float, u);
}
static __device__ __forceinline__ float bf2f_lo(u32 w) {
  return __builtin_bit_cast(float, w << 16);
}
static __device__ __forceinline__ float bf2f_hi(u32 w) {
  return __builtin_bit_cast(float, w & 0xffff0000u);
}
// pack 2 fp32 -> packed bf16x2; .x = low u16
static __device__ __forceinline__ u32 pk2(float a, float b) {
  __hip_bfloat162 h = __float22bfloat162_rn(make_float2(a, b));
  union { __hip_bfloat162 h; u32 u; } cv;
  cv.h = h;
  return cv.u;
}

// Gather one MFMA weight fragment: lane (q,c) element j holds W[r0+j][col].
// Used as the A operand (A[m=col][k=r0+j] of W^T).
static __device__ __forceinline__ bf16x8 load_wfrag(const void* W, bool isbf,
                                                    int N, int r0, int col) {
  union { bf16x8 v; u16 s[8]; } u;
  if (isbf) {
    const u16* p = (const u16*)W;
#pragma unroll
    for (int j = 0; j < 8; ++j) u.s[j] = p[(r0 + j) * N + col];
  } else {
    const float* p = (const float*)W;
#pragma unroll
    for (int j = 0; j < 8; ++j) u.s[j] = f2bf(p[(r0 + j) * N + col]);
  }
  return u.v;
}
static __device__ __forceinline__ float ldb(const void* p, bool isbf, int i) {
  return isbf ? bf2f(((const u16*)p)[i]) : ((const float*)p)[i];
}

// ---------------------------------------------------------------------------
// Fused NeuralODE, transposed world: z^T = W^T @ h^T per GEMM.
// 512 threads = 8 waves, 8-way feature split (R4 structure, proven 2 waves/
// SIMD at ~130 arch VGPRs):
//   H2-feats: wave w owns [32w,32w+32) (2 m-tiles)
//   H -feats: wave w owns [16w,16w+16) (1 m-tile)
// R7 lesson: W=4 dual-tile ILP spilled (weights 288 + dual state > budget).
// This round: ILP the register-cheap way — batch tile 64 (nt=4) in the W=8
// structure. 4 independent ds_read->MFMA chains per kt, barriers per batch
// element halved (3 per 64 rows vs 3 per 32). Per-element fp32 op sequence
// bitwise-identical to R4's PASS (batch columns are independent).
// Cold frags (wef/wdf, enc/dec biases) are loaded where used, per tile iter.
// ---------------------------------------------------------------------------
__global__ __launch_bounds__(512, 2) void node_main(
    const void* __restrict__ xv, void* __restrict__ outv,
    const void* __restrict__ Wenc, const void* __restrict__ benc,
    const void* __restrict__ W1, const void* __restrict__ b1,
    const void* __restrict__ W2, const void* __restrict__ b2,
    const void* __restrict__ W3, const void* __restrict__ b3,
    const void* __restrict__ Wdec, const void* __restrict__ bdec) {
  constexpr int STR = 264;  // 256 + 8 pad (keeps 16B alignment of fragments)
  __shared__ __align__(16) u16 zbA[64 * STR];  // 33.8 KB
  __shared__ __align__(16) u16 zbB[64 * STR];

  const int tid = threadIdx.x;
  const int w = tid >> 6, L = tid & 63;   // w in 0..7
  const int q = L >> 4, c = L & 15;
  const float dt = 0.05f;

  // ---- runtime dtype detection (uniform): bf16 -> low u16 of u32 words of
  // W_enc has bf16-exponent in [110,124] ~always; f32 -> ~6%. ----
  int cnt = 0;
  {
    const unsigned* wu = (const unsigned*)Wenc;
#pragma unroll 1
    for (int i = 0; i < 64; ++i) {
      unsigned e = (wu[i] >> 7) & 0xFFu;
      cnt += (e >= 110u && e <= 124u) ? 1 : 0;
    }
  }
  const bool isbf = (cnt >= 32);

  // ---- hot-loop weight A-frags (per-wave feature slice), 128 VGPRs ----
  bf16x8 w1f[4][2], w2f[8][2], w3f[8];
#pragma unroll
  for (int kt = 0; kt < 4; ++kt)
#pragma unroll
    for (int mt = 0; mt < 2; ++mt)
      w1f[kt][mt] = load_wfrag(W1, isbf, 256, kt * 32 + q * 8, 32 * w + mt * 16 + c);
#pragma unroll
  for (int kt = 0; kt < 8; ++kt)
#pragma unroll
    for (int mt = 0; mt < 2; ++mt)
      w2f[kt][mt] = load_wfrag(W2, isbf, 256, kt * 32 + q * 8, 32 * w + mt * 16 + c);
#pragma unroll
  for (int kt = 0; kt < 8; ++kt)
    w3f[kt] = load_wfrag(W3, isbf, 128, kt * 32 + q * 8, 16 * w + c);

  // ---- hot-loop biases, packed bf16 pairs ----
  u32 b1p[2][2], b2p[2][2], b3p[2];
#pragma unroll
  for (int mt = 0; mt < 2; ++mt) {
    int base = 32 * w + 16 * mt + 4 * q;
    b1p[mt][0] = pk2(ldb(b1, isbf, base + 0), ldb(b1, isbf, base + 1));
    b1p[mt][1] = pk2(ldb(b1, isbf, base + 2), ldb(b1, isbf, base + 3));
    b2p[mt][0] = pk2(ldb(b2, isbf, base + 0), ldb(b2, isbf, base + 1));
    b2p[mt][1] = pk2(ldb(b2, isbf, base + 2), ldb(b2, isbf, base + 3));
  }
  b3p[0] = pk2(ldb(b3, isbf, 16 * w + 4 * q + 0), ldb(b3, isbf, 16 * w + 4 * q + 1));
  b3p[1] = pk2(ldb(b3, isbf, 16 * w + 4 * q + 2), ldb(b3, isbf, 16 * w + 4 * q + 3));

  float h[4][4], r[4][4];  // state: feats 16w+4q+i, batch nt*16+c (nt=0..3)

  // One f-eval over 64 batch rows: htmp in P -> z1 in Q -> z2 in P ->
  // k (regs) -> htmp' in Q. Call sites alternate P/Q.
  auto feval = [&](int j, u16* __restrict__ P, u16* __restrict__ Q)
      __attribute__((always_inline)) {
    // ---- GEMM1: z1 = tanh(W1^T @ htmp + b1), K=128, out 2mt x 4nt ----
    f32x4 acc[2][4];
#pragma unroll
    for (int mt = 0; mt < 2; ++mt) {
      f32x4 bi = (f32x4){bf2f_lo(b1p[mt][0]), bf2f_hi(b1p[mt][0]),
                         bf2f_lo(b1p[mt][1]), bf2f_hi(b1p[mt][1])};
#pragma unroll
      for (int nt = 0; nt < 4; ++nt) acc[mt][nt] = bi;
    }
#pragma unroll
    for (int kt = 0; kt < 4; ++kt) {
      bf16x8 bb[4];
#pragma unroll
      for (int nt = 0; nt < 4; ++nt)
        bb[nt] = *(const bf16x8*)(P + (nt * 16 + c) * STR + kt * 32 + 8 * q);
#pragma unroll
      for (int mt = 0; mt < 2; ++mt)
#pragma unroll
        for (int nt = 0; nt < 4; ++nt)
          acc[mt][nt] = MFMA16(w1f[kt][mt], bb[nt], acc[mt][nt]);
    }
#pragma unroll
    for (int mt = 0; mt < 2; ++mt)
#pragma unroll
      for (int nt = 0; nt < 4; ++nt) {
        float t0 = fast_tanh(acc[mt][nt][0]), t1 = fast_tanh(acc[mt][nt][1]);
        float t2 = fast_tanh(acc[mt][nt][2]), t3 = fast_tanh(acc[mt][nt][3]);
        uint2 v; v.x = pk2(t0, t1); v.y = pk2(t2, t3);
        *(uint2*)(Q + (nt * 16 + c) * STR + 32 * w + 16 * mt + 4 * q) = v;
      }
    __syncthreads();

    // ---- GEMM2: z2 = tanh(W2^T @ z1 + b2), K=256 ----
#pragma unroll
    for (int mt = 0; mt < 2; ++mt) {
      f32x4 bi = (f32x4){bf2f_lo(b2p[mt][0]), bf2f_hi(b2p[mt][0]),
                         bf2f_lo(b2p[mt][1]), bf2f_hi(b2p[mt][1])};
#pragma unroll
      for (int nt = 0; nt < 4; ++nt) acc[mt][nt] = bi;
    }
#pragma unroll
    for (int kt = 0; kt < 8; ++kt) {
      bf16x8 bb[4];
#pragma unroll
      for (int nt = 0; nt < 4; ++nt)
        bb[nt] = *(const bf16x8*)(Q + (nt * 16 + c) * STR + kt * 32 + 8 * q);
#pragma unroll
      for (int mt = 0; mt < 2; ++mt)
#pragma unroll
        for (int nt = 0; nt < 4; ++nt)
          acc[mt][nt] = MFMA16(w2f[kt][mt], bb[nt], acc[mt][nt]);
    }
    // After the GEMM1 barrier no wave reads P until the barrier below, so
    // overwriting P here is race-free.
#pragma unroll
    for (int mt = 0; mt < 2; ++mt)
#pragma unroll
      for (int nt = 0; nt < 4; ++nt) {
        float t0 = fast_tanh(acc[mt][nt][0]), t1 = fast_tanh(acc[mt][nt][1]);
        float t2 = fast_tanh(acc[mt][nt][2]), t3 = fast_tanh(acc[mt][nt][3]);
        uint2 v; v.x = pk2(t0, t1); v.y = pk2(t2, t3);
        *(uint2*)(P + (nt * 16 + c) * STR + 32 * w + 16 * mt + 4 * q) = v;
      }
    __syncthreads();

    // ---- GEMM3: k = W3^T @ z2 + b3, K=256, out 1mt x 4nt ----
    f32x4 ak[4];
    {
      f32x4 bi = (f32x4){bf2f_lo(b3p[0]), bf2f_hi(b3p[0]),
                         bf2f_lo(b3p[1]), bf2f_hi(b3p[1])};
#pragma unroll
      for (int nt = 0; nt < 4; ++nt) ak[nt] = bi;
    }
#pragma unroll
    for (int kt = 0; kt < 8; ++kt) {
      bf16x8 bb[4];
#pragma unroll
      for (int nt = 0; nt < 4; ++nt)
        bb[nt] = *(const bf16x8*)(P + (nt * 16 + c) * STR + kt * 32 + 8 * q);
#pragma unroll
      for (int nt = 0; nt < 4; ++nt)
        ak[nt] = MFMA16(w3f[kt], bb[nt], ak[nt]);
    }

    // ---- RK4 bookkeeping + write next htmp to Q (j literal -> folds) ----
    const float wc = (j == 1 || j == 2) ? 2.f : 1.f;
    const float cc = (j == 2) ? dt : 0.5f * dt;
#pragma unroll
    for (int nt = 0; nt < 4; ++nt) {
      float ht[4];
#pragma unroll
      for (int i = 0; i < 4; ++i) {
        float kv = ak[nt][i];
        float rv = (j == 0) ? kv : r[nt][i] + wc * kv;
        r[nt][i] = rv;
        if (j == 3) {
          h[nt][i] += (dt / 6.f) * rv;
          ht[i] = h[nt][i];
        } else {
          ht[i] = h[nt][i] + cc * kv;
        }
      }
      uint2 v; v.x = pk2(ht[0], ht[1]); v.y = pk2(ht[2], ht[3]);
      *(uint2*)(Q + (nt * 16 + c) * STR + 16 * w + 4 * q) = v;
    }
    __syncthreads();
  };

#pragma unroll 1
  for (int tile = blockIdx.x; tile < 1024; tile += 512) {
    const int row0 = tile * 64;

    // ---- encoder: h0 = tanh(Wenc^T @ x^T + benc) -> regs + zbA ----
    // wef/bep are cold: loaded here, liveness ends at the end of this block.
    {
      bf16x8 wef[2];
#pragma unroll
      for (int kt = 0; kt < 2; ++kt)
        wef[kt] = load_wfrag(Wenc, isbf, 128, kt * 32 + q * 8, 16 * w + c);
      f32x4 he[4];
      {
        int base = 16 * w + 4 * q;
        f32x4 bi = (f32x4){ldb(benc, isbf, base + 0), ldb(benc, isbf, base + 1),
                           ldb(benc, isbf, base + 2), ldb(benc, isbf, base + 3)};
#pragma unroll
        for (int nt = 0; nt < 4; ++nt) he[nt] = bi;
      }
#pragma unroll
      for (int kt = 0; kt < 2; ++kt)
#pragma unroll
        for (int nt = 0; nt < 4; ++nt) {
          bf16x8 a;
          const int off = (row0 + nt * 16 + c) * 64 + kt * 32 + q * 8;
          if (isbf) {
            a = *(const bf16x8*)((const u16*)xv + off);
          } else {
            union { bf16x8 v; u16 s[8]; } u;
            const float* p = (const float*)xv + off;
#pragma unroll
            for (int j = 0; j < 8; ++j) u.s[j] = f2bf(p[j]);
            a = u.v;
          }
          he[nt] = MFMA16(wef[kt], a, he[nt]);
        }
#pragma unroll
      for (int nt = 0; nt < 4; ++nt) {
#pragma unroll
        for (int i = 0; i < 4; ++i) h[nt][i] = fast_tanh(he[nt][i]);
        uint2 v;
        v.x = pk2(h[nt][0], h[nt][1]);
        v.y = pk2(h[nt][2], h[nt][3]);
        *(uint2*)(zbA + (nt * 16 + c) * STR + 16 * w + 4 * q) = v;
      }
    }
    __syncthreads();

#pragma unroll 1
    for (int s = 0; s < 20; ++s) {
      feval(0, zbA, zbB);
      feval(1, zbB, zbA);
      feval(2, zbA, zbB);
      feval(3, zbB, zbA);
    }

    // ---- decoder: out = Wdec^T @ hT + bdec, hT in zbA (K=128) ----
    // wave w -> out-feat tile (w>>1) (16 feats), batch half (w&1) (32 rows).
    {
      bf16x8 wdf[4];
#pragma unroll
      for (int kt = 0; kt < 4; ++kt)
        wdf[kt] = load_wfrag(Wdec, isbf, 64, kt * 32 + q * 8, (w >> 1) * 16 + c);
      f32x4 ad[2];
      {
        int base = (w >> 1) * 16 + 4 * q;
        f32x4 bi = (f32x4){ldb(bdec, isbf, base + 0), ldb(bdec, isbf, base + 1),
                           ldb(bdec, isbf, base + 2), ldb(bdec, isbf, base + 3)};
        ad[0] = bi; ad[1] = bi;
      }
#pragma unroll
      for (int kt = 0; kt < 4; ++kt) {
#pragma unroll
        for (int half = 0; half < 2; ++half) {
          const int b = ((w & 1) * 2 + half) * 16 + c;  // batch row in tile
          bf16x8 bb = *(const bf16x8*)(zbA + b * STR + kt * 32 + 8 * q);
          ad[half] = MFMA16(wdf[kt], bb, ad[half]);
        }
      }
#pragma unroll
      for (int half = 0; half < 2; ++half) {
        const int ob = row0 + ((w & 1) * 2 + half) * 16 + c;  // batch row
        const int of = (w >> 1) * 16 + 4 * q;                 // feature col
        if (isbf) {
          uint2 v; v.x = pk2(ad[half][0], ad[half][1]);
          v.y = pk2(ad[half][2], ad[half][3]);
          *(uint2*)((u16*)outv + ob * 64 + of) = v;
        } else {
#pragma unroll
          for (int i = 0; i < 4; ++i)
            ((float*)outv)[ob * 64 + of + i] = ad[half][i];
        }
      }
    }
    __syncthreads();  // protect zbA before next tile's encoder writes
  }
}

extern "C" void kernel_launch(void* const* d_in, const int* in_sizes, int n_in,
                              void* d_out, int out_size, void* d_ws, size_t ws_size,
                              hipStream_t stream) {
  (void)in_sizes; (void)n_in; (void)out_size; (void)d_ws; (void)ws_size;
  node_main<<<512, 512, 0, stream>>>(
      d_in[0], d_out,
      d_in[1], d_in[2],   // W_enc, b_enc
      d_in[3], d_in[4],   // W1, b1
      d_in[5], d_in[6],   // W2, b2
      d_in[7], d_in[8],   // W3, b3
      d_in[9], d_in[10]); // W_dec, b_dec
}